// Round 6
// baseline (731.303 us; speedup 1.0000x reference)
//
#include <hip/hip_runtime.h>
#include <math.h>

// B=64, S=64, H_DIM=768, N_HEADS=12, D=64. All I/O f32.
// ws (float offsets):
//   qkv [64*12*64*192] @0 (9437184)            dead after k_attn
//   part[32][64][4096] @0 (8388608)            reuses dead qkv region
//   Zh  bf16[64][49152] @9437184  (1572864 float-slots)
//   Zl  bf16[64][49152] @11010048 (1572864 float-slots)
// d_out (f32): y [262144] then masked_scores [3145728]
// Masked positions: ref=-inf -> write finite NEG_BIG (never materialize inf;
// finite-math folds ==-INFINITY). expf(NEG_BIG - m) == 0 exactly.
// GEMMs: bf16 MFMA split precision  A*B ~= Ah*Bh + Ah*Bl + Al*Bh (~2^-17 rel).
// mfma_f32_16x16x32_bf16: A row=ln&15,k=(ln>>4)*8+j; B col=ln&15,k same;
// C/D col=ln&15, row=(ln>>4)*4+reg.

#define NEG_BIG (-1.0e30f)

typedef __attribute__((ext_vector_type(8))) short bf16x8;
typedef __attribute__((ext_vector_type(4))) float f32x4;

static __device__ __forceinline__ void split_bf16(float x, unsigned short& h, unsigned short& l) {
    unsigned u = __builtin_bit_cast(unsigned, x);
    unsigned hr = (u + 0x7FFFu + ((u >> 16) & 1u)) & 0xFFFF0000u;   // RNE hi, as f32 bits
    h = (unsigned short)(hr >> 16);
    float lf = x - __builtin_bit_cast(float, hr);                   // exact residual
    unsigned ul = __builtin_bit_cast(unsigned, lf);
    l = (unsigned short)((ul + 0x7FFFu + ((ul >> 16) & 1u)) >> 16); // RNE lo
}

static __device__ __forceinline__ void split8(const float4 a, const float4 b, bf16x8& h, bf16x8& l) {
    unsigned short hh, ll;
    split_bf16(a.x, hh, ll); h[0] = (short)hh; l[0] = (short)ll;
    split_bf16(a.y, hh, ll); h[1] = (short)hh; l[1] = (short)ll;
    split_bf16(a.z, hh, ll); h[2] = (short)hh; l[2] = (short)ll;
    split_bf16(a.w, hh, ll); h[3] = (short)hh; l[3] = (short)ll;
    split_bf16(b.x, hh, ll); h[4] = (short)hh; l[4] = (short)ll;
    split_bf16(b.y, hh, ll); h[5] = (short)hh; l[5] = (short)ll;
    split_bf16(b.z, hh, ll); h[6] = (short)hh; l[6] = (short)ll;
    split_bf16(b.w, hh, ll); h[7] = (short)hh; l[7] = (short)ll;
}

// ---------------- Kernel 1: QKV projection GEMM (MFMA bf16x3) ----------------
__global__ __launch_bounds__(256) void k_qkv(const float* __restrict__ X,
                                             const float* __restrict__ Wp,
                                             float* __restrict__ qkv) {
    __shared__ unsigned short Ah[128][72], Al[128][72];
    __shared__ unsigned short Bh[128][72], Bl[128][72];
    const int t  = threadIdx.x;
    const int wv = t >> 6, ln = t & 63;
    const int lr = ln & 15;
    const int kq = (ln >> 4) * 8;
    const int m0 = blockIdx.y * 128;
    const int j0 = blockIdx.x * 128;

    const f32x4 zero4 = {0.f, 0.f, 0.f, 0.f};
    f32x4 acc[2][8];
#pragma unroll
    for (int rt = 0; rt < 2; ++rt)
#pragma unroll
        for (int ct = 0; ct < 8; ++ct) acc[rt][ct] = zero4;

    for (int k0 = 0; k0 < 768; k0 += 64) {
#pragma unroll
        for (int i = 0; i < 8; ++i) {
            const int q   = t + 256 * i;
            const int row = q >> 4;
            const int kc  = (q & 15) * 4;
            float4 xa = *reinterpret_cast<const float4*>(&X[(size_t)(m0 + row) * 768 + k0 + kc]);
            ushort4 h, l;
            split_bf16(xa.x, h.x, l.x); split_bf16(xa.y, h.y, l.y);
            split_bf16(xa.z, h.z, l.z); split_bf16(xa.w, h.w, l.w);
            *reinterpret_cast<ushort4*>(&Ah[row][kc]) = h;
            *reinterpret_cast<ushort4*>(&Al[row][kc]) = l;
            float4 wb = *reinterpret_cast<const float4*>(&Wp[(size_t)(j0 + row) * 768 + k0 + kc]);
            split_bf16(wb.x, h.x, l.x); split_bf16(wb.y, h.y, l.y);
            split_bf16(wb.z, h.z, l.z); split_bf16(wb.w, h.w, l.w);
            *reinterpret_cast<ushort4*>(&Bh[row][kc]) = h;
            *reinterpret_cast<ushort4*>(&Bl[row][kc]) = l;
        }
        __syncthreads();
#pragma unroll
        for (int ks = 0; ks < 2; ++ks) {
            const int kb = ks * 32 + kq;
            bf16x8 ah[2], al[2];
#pragma unroll
            for (int rt = 0; rt < 2; ++rt) {
                const int row = wv * 32 + rt * 16 + lr;
                ah[rt] = *reinterpret_cast<const bf16x8*>(&Ah[row][kb]);
                al[rt] = *reinterpret_cast<const bf16x8*>(&Al[row][kb]);
            }
#pragma unroll
            for (int ct = 0; ct < 8; ++ct) {
                const int col = ct * 16 + lr;
                bf16x8 bh = *reinterpret_cast<const bf16x8*>(&Bh[col][kb]);
                bf16x8 bl = *reinterpret_cast<const bf16x8*>(&Bl[col][kb]);
#pragma unroll
                for (int rt = 0; rt < 2; ++rt) {
                    acc[rt][ct] = __builtin_amdgcn_mfma_f32_16x16x32_bf16(ah[rt], bh, acc[rt][ct], 0, 0, 0);
                    acc[rt][ct] = __builtin_amdgcn_mfma_f32_16x16x32_bf16(ah[rt], bl, acc[rt][ct], 0, 0, 0);
                    acc[rt][ct] = __builtin_amdgcn_mfma_f32_16x16x32_bf16(al[rt], bh, acc[rt][ct], 0, 0, 0);
                }
            }
        }
        __syncthreads();
    }

    const int rbase = (ln >> 4) * 4;
#pragma unroll
    for (int rt = 0; rt < 2; ++rt)
#pragma unroll
        for (int ct = 0; ct < 8; ++ct)
#pragma unroll
            for (int r = 0; r < 4; ++r) {
                const int m = m0 + wv * 32 + rt * 16 + rbase + r;
                const int j = j0 + ct * 16 + lr;
                const int b = m >> 6, s = m & 63;
                const int n = j / 192, f = j % 192;
                qkv[(((size_t)b * 12 + n) * 64 + s) * 192 + f] = acc[rt][ct][r];
            }
}

// ---------------- Kernel 2: attention per (b,n), MFMA bf16x3 ----------------
// Writes masked scores (f32, finite sentinel) and pre-split ctx (Zh/Zl bf16).
__global__ __launch_bounds__(256) void k_attn(const float* __restrict__ qkv,
                                              float* __restrict__ msk,
                                              unsigned short* __restrict__ Zh,
                                              unsigned short* __restrict__ Zl) {
    __shared__ unsigned short Qh[64][72], Ql[64][72];
    __shared__ unsigned short Kh[64][72], Kl[64][72];
    __shared__ unsigned short Vth[64][72], Vtl[64][72];   // V transposed: [d][s]
    __shared__ unsigned short Ph[64][72], Pl[64][72];
    const int t  = threadIdx.x;
    const int wv = t >> 6, ln = t & 63;
    const int lr = ln & 15;           // fragment row/col lane index
    const int kq = (ln >> 4) * 8;     // fragment k offset
    const int rbase = (ln >> 4) * 4;  // C/D row base
    const int bn = blockIdx.x;
    const int bb = bn / 12, nn = bn % 12;
    const float* base = qkv + (size_t)bn * 12288;

    // stage q,k (row-major) and v (transposed), split to bf16 hi/lo
#pragma unroll
    for (int i = 0; i < 12; ++i) {
        const int q    = t + 256 * i;        // 0..3071 float4s
        const int row  = q / 48;
        const int fpos = (q % 48) * 4;       // 0..188
        const int sec  = fpos >> 6;          // 0=q 1=k 2=v
        const int d0   = fpos & 63;
        float4 v4 = *reinterpret_cast<const float4*>(&base[(size_t)row * 192 + fpos]);
        ushort4 h, l;
        split_bf16(v4.x, h.x, l.x); split_bf16(v4.y, h.y, l.y);
        split_bf16(v4.z, h.z, l.z); split_bf16(v4.w, h.w, l.w);
        if (sec == 0) {
            *reinterpret_cast<ushort4*>(&Qh[row][d0]) = h;
            *reinterpret_cast<ushort4*>(&Ql[row][d0]) = l;
        } else if (sec == 1) {
            *reinterpret_cast<ushort4*>(&Kh[row][d0]) = h;
            *reinterpret_cast<ushort4*>(&Kl[row][d0]) = l;
        } else {
            Vth[d0 + 0][row] = h.x; Vtl[d0 + 0][row] = l.x;
            Vth[d0 + 1][row] = h.y; Vtl[d0 + 1][row] = l.y;
            Vth[d0 + 2][row] = h.z; Vtl[d0 + 2][row] = l.z;
            Vth[d0 + 3][row] = h.w; Vtl[d0 + 3][row] = l.w;
        }
    }
    __syncthreads();

    // ---- scores S = Q K^T / 8 : wave wv owns rows [wv*16, wv*16+16) ----
    const f32x4 zero4 = {0.f, 0.f, 0.f, 0.f};
    f32x4 acc[4];
#pragma unroll
    for (int ct = 0; ct < 4; ++ct) acc[ct] = zero4;
#pragma unroll
    for (int ks = 0; ks < 2; ++ks) {
        const int kb = ks * 32 + kq;
        bf16x8 qh = *reinterpret_cast<const bf16x8*>(&Qh[wv * 16 + lr][kb]);
        bf16x8 ql = *reinterpret_cast<const bf16x8*>(&Ql[wv * 16 + lr][kb]);
#pragma unroll
        for (int ct = 0; ct < 4; ++ct) {
            bf16x8 kh = *reinterpret_cast<const bf16x8*>(&Kh[ct * 16 + lr][kb]);
            bf16x8 kl = *reinterpret_cast<const bf16x8*>(&Kl[ct * 16 + lr][kb]);
            acc[ct] = __builtin_amdgcn_mfma_f32_16x16x32_bf16(qh, kh, acc[ct], 0, 0, 0);
            acc[ct] = __builtin_amdgcn_mfma_f32_16x16x32_bf16(qh, kl, acc[ct], 0, 0, 0);
            acc[ct] = __builtin_amdgcn_mfma_f32_16x16x32_bf16(ql, kh, acc[ct], 0, 0, 0);
        }
    }

    // mask + write scores + softmax (per-row over 16 lanes x 4 ct)
    float s_[4][4];
#pragma unroll
    for (int ct = 0; ct < 4; ++ct)
#pragma unroll
        for (int r = 0; r < 4; ++r) {
            const int row = wv * 16 + rbase + r;
            const int col = ct * 16 + lr;
            float s = (col > row) ? NEG_BIG : acc[ct][r] * 0.125f;
            s_[ct][r] = s;
            msk[(size_t)bn * 4096 + (size_t)row * 64 + col] = s;
        }
    float m[4], sum[4], p[4][4];
#pragma unroll
    for (int r = 0; r < 4; ++r)
        m[r] = fmaxf(fmaxf(s_[0][r], s_[1][r]), fmaxf(s_[2][r], s_[3][r]));
#pragma unroll
    for (int off = 1; off <= 8; off <<= 1)
#pragma unroll
        for (int r = 0; r < 4; ++r) m[r] = fmaxf(m[r], __shfl_xor(m[r], off));
#pragma unroll
    for (int r = 0; r < 4; ++r) sum[r] = 0.f;
#pragma unroll
    for (int ct = 0; ct < 4; ++ct)
#pragma unroll
        for (int r = 0; r < 4; ++r) { p[ct][r] = expf(s_[ct][r] - m[r]); sum[r] += p[ct][r]; }
#pragma unroll
    for (int off = 1; off <= 8; off <<= 1)
#pragma unroll
        for (int r = 0; r < 4; ++r) sum[r] += __shfl_xor(sum[r], off);
#pragma unroll
    for (int ct = 0; ct < 4; ++ct)
#pragma unroll
        for (int r = 0; r < 4; ++r) {
            const float pv = p[ct][r] * (1.f / sum[r]);
            unsigned short h, l;
            split_bf16(pv, h, l);
            Ph[wv * 16 + rbase + r][ct * 16 + lr] = h;
            Pl[wv * 16 + rbase + r][ct * 16 + lr] = l;
        }
    // intra-wave LDS dependency only (wave reads back its own 16 rows)

    // ---- ctx = P V : A = P rows, B = Vt[d][s] ----
    f32x4 o_[4];
#pragma unroll
    for (int ct = 0; ct < 4; ++ct) o_[ct] = zero4;
#pragma unroll
    for (int ks = 0; ks < 2; ++ks) {
        const int kb = ks * 32 + kq;
        bf16x8 ph = *reinterpret_cast<const bf16x8*>(&Ph[wv * 16 + lr][kb]);
        bf16x8 pl = *reinterpret_cast<const bf16x8*>(&Pl[wv * 16 + lr][kb]);
#pragma unroll
        for (int ct = 0; ct < 4; ++ct) {
            bf16x8 vh = *reinterpret_cast<const bf16x8*>(&Vth[ct * 16 + lr][kb]);
            bf16x8 vl = *reinterpret_cast<const bf16x8*>(&Vtl[ct * 16 + lr][kb]);
            o_[ct] = __builtin_amdgcn_mfma_f32_16x16x32_bf16(ph, vh, o_[ct], 0, 0, 0);
            o_[ct] = __builtin_amdgcn_mfma_f32_16x16x32_bf16(ph, vl, o_[ct], 0, 0, 0);
            o_[ct] = __builtin_amdgcn_mfma_f32_16x16x32_bf16(pl, vh, o_[ct], 0, 0, 0);
        }
    }
    // write ctx pre-split: z_flat[b][n*4096 + s*64 + d]
#pragma unroll
    for (int ct = 0; ct < 4; ++ct)
#pragma unroll
        for (int r = 0; r < 4; ++r) {
            const int srow = wv * 16 + rbase + r;
            const int d    = ct * 16 + lr;
            const size_t zi = (size_t)bb * 49152 + nn * 4096 + srow * 64 + d;
            unsigned short h, l;
            split_bf16(o_[ct][r], h, l);
            Zh[zi] = h; Zl[zi] = l;
        }
}

// ---------------- Kernel 3: output projection — register-direct MFMA ----------------
// part[ksp][b][o] = sum_k Z[b][k] W[o][k]; KSPLIT=32, chunk=1536, no LDS/barriers.
__global__ __launch_bounds__(256) void k_lin(const unsigned short* __restrict__ Zh,
                                             const unsigned short* __restrict__ Zl,
                                             const float* __restrict__ W,
                                             float* __restrict__ part) {
    const int t  = threadIdx.x;
    const int wv = t >> 6, ln = t & 63;
    const int lr = ln & 15;
    const int kq = (ln >> 4) * 8;
    const int o0   = blockIdx.x * 64;
    const int ksp  = blockIdx.y;
    const int kbeg = ksp * 1536;

    const int ocol = o0 + wv * 16 + lr;
    const float* wp = W + (size_t)ocol * 49152 + kbeg + kq;
    const unsigned short* zh0 = Zh + (size_t)lr * 49152 + kbeg + kq;        // rt=0 row
    const unsigned short* zl0 = Zl + (size_t)lr * 49152 + kbeg + kq;

    const f32x4 zero4 = {0.f, 0.f, 0.f, 0.f};
    f32x4 acc[4];
#pragma unroll
    for (int rt = 0; rt < 4; ++rt) acc[rt] = zero4;

    float4 cw0 = *reinterpret_cast<const float4*>(wp);
    float4 cw1 = *reinterpret_cast<const float4*>(wp + 4);
    for (int kk = 0; kk < 48; ++kk) {
        const int kn = (kk + 1 < 48) ? (kk + 1) : kk;   // clamped prefetch (avoid OOB)
        float4 nw0 = *reinterpret_cast<const float4*>(wp + kn * 32);
        float4 nw1 = *reinterpret_cast<const float4*>(wp + kn * 32 + 4);
        bf16x8 wh, wl;
        split8(cw0, cw1, wh, wl);
        const int koff = kk * 32;
#pragma unroll
        for (int rt = 0; rt < 4; ++rt) {
            bf16x8 ah = *reinterpret_cast<const bf16x8*>(zh0 + (size_t)rt * 16 * 49152 + koff);
            bf16x8 al = *reinterpret_cast<const bf16x8*>(zl0 + (size_t)rt * 16 * 49152 + koff);
            acc[rt] = __builtin_amdgcn_mfma_f32_16x16x32_bf16(ah, wh, acc[rt], 0, 0, 0);
            acc[rt] = __builtin_amdgcn_mfma_f32_16x16x32_bf16(ah, wl, acc[rt], 0, 0, 0);
            acc[rt] = __builtin_amdgcn_mfma_f32_16x16x32_bf16(al, wh, acc[rt], 0, 0, 0);
        }
        cw0 = nw0; cw1 = nw1;
    }

    const int rbase = (ln >> 4) * 4;
#pragma unroll
    for (int rt = 0; rt < 4; ++rt)
#pragma unroll
        for (int r = 0; r < 4; ++r) {
            const int brow = rt * 16 + rbase + r;
            part[((size_t)ksp * 64 + brow) * 4096 + ocol] = acc[rt][r];
        }
}

// ---------------- Kernel 4: reduce 32 split-K partials + bias ----------------
__global__ __launch_bounds__(256) void k_reduce(const float* __restrict__ part,
                                                const float* __restrict__ bias,
                                                float* __restrict__ y) {
    const int idx = blockIdx.x * 256 + threadIdx.x;   // 0..262143
    const int o = idx & 4095;
    const int b = idx >> 12;
    float s = bias[o];
#pragma unroll
    for (int ksp = 0; ksp < 32; ++ksp)
        s += part[((size_t)ksp * 64 + b) * 4096 + o];
    y[idx] = s;
}

extern "C" void kernel_launch(void* const* d_in, const int* in_sizes, int n_in,
                              void* d_out, int out_size, void* d_ws, size_t ws_size,
                              hipStream_t stream) {
    const float* x  = (const float*)d_in[0];
    const float* Wp = (const float*)d_in[1];
    const float* Wl = (const float*)d_in[2];
    const float* bl = (const float*)d_in[3];
    float* out = (float*)d_out;
    float* ws  = (float*)d_ws;

    float* qkv  = ws;                                        // 9437184 floats (dead after k_attn)
    float* part = ws;                                        // 8388608 floats (reuses qkv region)
    unsigned short* Zh = (unsigned short*)(ws + 9437184);    // 3145728 bf16
    unsigned short* Zl = (unsigned short*)(ws + 11010048);   // 3145728 bf16
    float* y    = out;
    float* msk  = out + 262144;

    hipLaunchKernelGGL(k_qkv,    dim3(18, 32), dim3(256), 0, stream, x, Wp, qkv);
    hipLaunchKernelGGL(k_attn,   dim3(768),    dim3(256), 0, stream, qkv, msk, Zh, Zl);
    hipLaunchKernelGGL(k_lin,    dim3(64, 32), dim3(256), 0, stream, Zh, Zl, Wl, part);
    hipLaunchKernelGGL(k_reduce, dim3(1024),   dim3(256), 0, stream, part, bl, y);
}

// Round 7
// 508.819 us; speedup vs baseline: 1.4373x; 1.4373x over previous
//
#include <hip/hip_runtime.h>
#include <math.h>

// B=64, S=64, H_DIM=768, N_HEADS=12, D=64. All I/O f32.
// ws (float offsets):
//   qkv [64*12*64*192] @0 (9437184)           dead after k_attn
//   part[32][64][4096] @0 (8388608)           reuses dead qkv region
//   Zh  bf16 frag-order @9437184  (1572864 float-slots)
//   Zl  bf16 frag-order @11010048 (1572864 float-slots)
// Z fragment order: element (b,k) of z_flat[64][49152] lives at
//   ((rt*1536 + kf)*64 + ln)*8 + j,  rt=b>>4, kf=k>>5, ln=((k>>3)&3)*16+(b&15), j=k&7
// so a wave's MFMA A-fragment (row=ln&15, k=(ln>>4)*8+j) is one contiguous
// 1KB read: base + ((rt*1536+kf)*64)*8, lane ln takes 16B at +ln*16.
// d_out (f32): y [262144] then masked_scores [3145728]
// Masked positions: ref=-inf -> write finite NEG_BIG (never materialize inf;
// finite-math folds ==-INFINITY). expf(NEG_BIG - m) == 0 exactly.
// GEMMs: bf16 MFMA split precision  A*B ~= Ah*Bh + Ah*Bl + Al*Bh (~2^-17 rel).
// mfma_f32_16x16x32_bf16: A row=ln&15,k=(ln>>4)*8+j; B col=ln&15,k same;
// C/D col=ln&15, row=(ln>>4)*4+reg.

#define NEG_BIG (-1.0e30f)

typedef __attribute__((ext_vector_type(8))) short bf16x8;
typedef __attribute__((ext_vector_type(4))) float f32x4;
typedef const __attribute__((address_space(1))) void gvoid_t;
typedef __attribute__((address_space(3))) void svoid_t;

static __device__ __forceinline__ void split_bf16(float x, unsigned short& h, unsigned short& l) {
    unsigned u = __builtin_bit_cast(unsigned, x);
    unsigned hr = (u + 0x7FFFu + ((u >> 16) & 1u)) & 0xFFFF0000u;   // RNE hi, as f32 bits
    h = (unsigned short)(hr >> 16);
    float lf = x - __builtin_bit_cast(float, hr);                   // exact residual
    unsigned ul = __builtin_bit_cast(unsigned, lf);
    l = (unsigned short)((ul + 0x7FFFu + ((ul >> 16) & 1u)) >> 16); // RNE lo
}

static __device__ __forceinline__ void split8(const float4 a, const float4 b, bf16x8& h, bf16x8& l) {
    unsigned short hh, ll;
    split_bf16(a.x, hh, ll); h[0] = (short)hh; l[0] = (short)ll;
    split_bf16(a.y, hh, ll); h[1] = (short)hh; l[1] = (short)ll;
    split_bf16(a.z, hh, ll); h[2] = (short)hh; l[2] = (short)ll;
    split_bf16(a.w, hh, ll); h[3] = (short)hh; l[3] = (short)ll;
    split_bf16(b.x, hh, ll); h[4] = (short)hh; l[4] = (short)ll;
    split_bf16(b.y, hh, ll); h[5] = (short)hh; l[5] = (short)ll;
    split_bf16(b.z, hh, ll); h[6] = (short)hh; l[6] = (short)ll;
    split_bf16(b.w, hh, ll); h[7] = (short)hh; l[7] = (short)ll;
}

// ---------------- Kernel 1: QKV projection GEMM (MFMA bf16x3) ----------------
__global__ __launch_bounds__(256) void k_qkv(const float* __restrict__ X,
                                             const float* __restrict__ Wp,
                                             float* __restrict__ qkv) {
    __shared__ unsigned short Ah[128][72], Al[128][72];
    __shared__ unsigned short Bh[128][72], Bl[128][72];
    const int t  = threadIdx.x;
    const int wv = t >> 6, ln = t & 63;
    const int lr = ln & 15;
    const int kq = (ln >> 4) * 8;
    const int m0 = blockIdx.y * 128;
    const int j0 = blockIdx.x * 128;

    const f32x4 zero4 = {0.f, 0.f, 0.f, 0.f};
    f32x4 acc[2][8];
#pragma unroll
    for (int rt = 0; rt < 2; ++rt)
#pragma unroll
        for (int ct = 0; ct < 8; ++ct) acc[rt][ct] = zero4;

    for (int k0 = 0; k0 < 768; k0 += 64) {
#pragma unroll
        for (int i = 0; i < 8; ++i) {
            const int q   = t + 256 * i;
            const int row = q >> 4;
            const int kc  = (q & 15) * 4;
            float4 xa = *reinterpret_cast<const float4*>(&X[(size_t)(m0 + row) * 768 + k0 + kc]);
            ushort4 h, l;
            split_bf16(xa.x, h.x, l.x); split_bf16(xa.y, h.y, l.y);
            split_bf16(xa.z, h.z, l.z); split_bf16(xa.w, h.w, l.w);
            *reinterpret_cast<ushort4*>(&Ah[row][kc]) = h;
            *reinterpret_cast<ushort4*>(&Al[row][kc]) = l;
            float4 wb = *reinterpret_cast<const float4*>(&Wp[(size_t)(j0 + row) * 768 + k0 + kc]);
            split_bf16(wb.x, h.x, l.x); split_bf16(wb.y, h.y, l.y);
            split_bf16(wb.z, h.z, l.z); split_bf16(wb.w, h.w, l.w);
            *reinterpret_cast<ushort4*>(&Bh[row][kc]) = h;
            *reinterpret_cast<ushort4*>(&Bl[row][kc]) = l;
        }
        __syncthreads();
#pragma unroll
        for (int ks = 0; ks < 2; ++ks) {
            const int kb = ks * 32 + kq;
            bf16x8 ah[2], al[2];
#pragma unroll
            for (int rt = 0; rt < 2; ++rt) {
                const int row = wv * 32 + rt * 16 + lr;
                ah[rt] = *reinterpret_cast<const bf16x8*>(&Ah[row][kb]);
                al[rt] = *reinterpret_cast<const bf16x8*>(&Al[row][kb]);
            }
#pragma unroll
            for (int ct = 0; ct < 8; ++ct) {
                const int col = ct * 16 + lr;
                bf16x8 bh = *reinterpret_cast<const bf16x8*>(&Bh[col][kb]);
                bf16x8 bl = *reinterpret_cast<const bf16x8*>(&Bl[col][kb]);
#pragma unroll
                for (int rt = 0; rt < 2; ++rt) {
                    acc[rt][ct] = __builtin_amdgcn_mfma_f32_16x16x32_bf16(ah[rt], bh, acc[rt][ct], 0, 0, 0);
                    acc[rt][ct] = __builtin_amdgcn_mfma_f32_16x16x32_bf16(ah[rt], bl, acc[rt][ct], 0, 0, 0);
                    acc[rt][ct] = __builtin_amdgcn_mfma_f32_16x16x32_bf16(al[rt], bh, acc[rt][ct], 0, 0, 0);
                }
            }
        }
        __syncthreads();
    }

    const int rbase = (ln >> 4) * 4;
#pragma unroll
    for (int rt = 0; rt < 2; ++rt)
#pragma unroll
        for (int ct = 0; ct < 8; ++ct)
#pragma unroll
            for (int r = 0; r < 4; ++r) {
                const int m = m0 + wv * 32 + rt * 16 + rbase + r;
                const int j = j0 + ct * 16 + lr;
                const int b = m >> 6, s = m & 63;
                const int n = j / 192, f = j % 192;
                qkv[(((size_t)b * 12 + n) * 64 + s) * 192 + f] = acc[rt][ct][r];
            }
}

// ---------------- Kernel 2: attention per (b,n), MFMA bf16x3 ----------------
// Writes masked scores (f32) and ctx pre-split in Z fragment order.
__global__ __launch_bounds__(256) void k_attn(const float* __restrict__ qkv,
                                              float* __restrict__ msk,
                                              unsigned short* __restrict__ Zh,
                                              unsigned short* __restrict__ Zl) {
    __shared__ unsigned short Qh[64][72], Ql[64][72];
    __shared__ unsigned short Kh[64][72], Kl[64][72];
    __shared__ unsigned short Vth[64][72], Vtl[64][72];   // V transposed: [d][s]
    __shared__ unsigned short Ph[64][72], Pl[64][72];
    const int t  = threadIdx.x;
    const int wv = t >> 6, ln = t & 63;
    const int lr = ln & 15;
    const int kq = (ln >> 4) * 8;
    const int rbase = (ln >> 4) * 4;
    const int bn = blockIdx.x;
    const int bb = bn / 12, nn = bn % 12;
    const float* base = qkv + (size_t)bn * 12288;

#pragma unroll
    for (int i = 0; i < 12; ++i) {
        const int q    = t + 256 * i;
        const int row  = q / 48;
        const int fpos = (q % 48) * 4;
        const int sec  = fpos >> 6;
        const int d0   = fpos & 63;
        float4 v4 = *reinterpret_cast<const float4*>(&base[(size_t)row * 192 + fpos]);
        ushort4 h, l;
        split_bf16(v4.x, h.x, l.x); split_bf16(v4.y, h.y, l.y);
        split_bf16(v4.z, h.z, l.z); split_bf16(v4.w, h.w, l.w);
        if (sec == 0) {
            *reinterpret_cast<ushort4*>(&Qh[row][d0]) = h;
            *reinterpret_cast<ushort4*>(&Ql[row][d0]) = l;
        } else if (sec == 1) {
            *reinterpret_cast<ushort4*>(&Kh[row][d0]) = h;
            *reinterpret_cast<ushort4*>(&Kl[row][d0]) = l;
        } else {
            Vth[d0 + 0][row] = h.x; Vtl[d0 + 0][row] = l.x;
            Vth[d0 + 1][row] = h.y; Vtl[d0 + 1][row] = l.y;
            Vth[d0 + 2][row] = h.z; Vtl[d0 + 2][row] = l.z;
            Vth[d0 + 3][row] = h.w; Vtl[d0 + 3][row] = l.w;
        }
    }
    __syncthreads();

    // ---- S = Q K^T / 8 ----
    const f32x4 zero4 = {0.f, 0.f, 0.f, 0.f};
    f32x4 acc[4];
#pragma unroll
    for (int ct = 0; ct < 4; ++ct) acc[ct] = zero4;
#pragma unroll
    for (int ks = 0; ks < 2; ++ks) {
        const int kb = ks * 32 + kq;
        bf16x8 qh = *reinterpret_cast<const bf16x8*>(&Qh[wv * 16 + lr][kb]);
        bf16x8 ql = *reinterpret_cast<const bf16x8*>(&Ql[wv * 16 + lr][kb]);
#pragma unroll
        for (int ct = 0; ct < 4; ++ct) {
            bf16x8 kh = *reinterpret_cast<const bf16x8*>(&Kh[ct * 16 + lr][kb]);
            bf16x8 kl = *reinterpret_cast<const bf16x8*>(&Kl[ct * 16 + lr][kb]);
            acc[ct] = __builtin_amdgcn_mfma_f32_16x16x32_bf16(qh, kh, acc[ct], 0, 0, 0);
            acc[ct] = __builtin_amdgcn_mfma_f32_16x16x32_bf16(qh, kl, acc[ct], 0, 0, 0);
            acc[ct] = __builtin_amdgcn_mfma_f32_16x16x32_bf16(ql, kh, acc[ct], 0, 0, 0);
        }
    }

    // mask + write scores + softmax
    float s_[4][4];
#pragma unroll
    for (int ct = 0; ct < 4; ++ct)
#pragma unroll
        for (int r = 0; r < 4; ++r) {
            const int row = wv * 16 + rbase + r;
            const int col = ct * 16 + lr;
            float s = (col > row) ? NEG_BIG : acc[ct][r] * 0.125f;
            s_[ct][r] = s;
            msk[(size_t)bn * 4096 + (size_t)row * 64 + col] = s;
        }
    float m[4], sum[4], p[4][4];
#pragma unroll
    for (int r = 0; r < 4; ++r)
        m[r] = fmaxf(fmaxf(s_[0][r], s_[1][r]), fmaxf(s_[2][r], s_[3][r]));
#pragma unroll
    for (int off = 1; off <= 8; off <<= 1)
#pragma unroll
        for (int r = 0; r < 4; ++r) m[r] = fmaxf(m[r], __shfl_xor(m[r], off));
#pragma unroll
    for (int r = 0; r < 4; ++r) sum[r] = 0.f;
#pragma unroll
    for (int ct = 0; ct < 4; ++ct)
#pragma unroll
        for (int r = 0; r < 4; ++r) { p[ct][r] = expf(s_[ct][r] - m[r]); sum[r] += p[ct][r]; }
#pragma unroll
    for (int off = 1; off <= 8; off <<= 1)
#pragma unroll
        for (int r = 0; r < 4; ++r) sum[r] += __shfl_xor(sum[r], off);
#pragma unroll
    for (int ct = 0; ct < 4; ++ct)
#pragma unroll
        for (int r = 0; r < 4; ++r) {
            const float pv = p[ct][r] * (1.f / sum[r]);
            unsigned short h, l;
            split_bf16(pv, h, l);
            Ph[wv * 16 + rbase + r][ct * 16 + lr] = h;
            Pl[wv * 16 + rbase + r][ct * 16 + lr] = l;
        }
    // intra-wave LDS dependency only

    // ---- ctx = P V ----
    f32x4 o_[4];
#pragma unroll
    for (int ct = 0; ct < 4; ++ct) o_[ct] = zero4;
#pragma unroll
    for (int ks = 0; ks < 2; ++ks) {
        const int kb = ks * 32 + kq;
        bf16x8 ph = *reinterpret_cast<const bf16x8*>(&Ph[wv * 16 + lr][kb]);
        bf16x8 pl = *reinterpret_cast<const bf16x8*>(&Pl[wv * 16 + lr][kb]);
#pragma unroll
        for (int ct = 0; ct < 4; ++ct) {
            bf16x8 vh = *reinterpret_cast<const bf16x8*>(&Vth[ct * 16 + lr][kb]);
            bf16x8 vl = *reinterpret_cast<const bf16x8*>(&Vtl[ct * 16 + lr][kb]);
            o_[ct] = __builtin_amdgcn_mfma_f32_16x16x32_bf16(ph, vh, o_[ct], 0, 0, 0);
            o_[ct] = __builtin_amdgcn_mfma_f32_16x16x32_bf16(ph, vl, o_[ct], 0, 0, 0);
            o_[ct] = __builtin_amdgcn_mfma_f32_16x16x32_bf16(pl, vh, o_[ct], 0, 0, 0);
        }
    }
    // write ctx pre-split in Z FRAGMENT ORDER (see header)
    const int rt_z = bb >> 4;
#pragma unroll
    for (int ct = 0; ct < 4; ++ct)
#pragma unroll
        for (int r = 0; r < 4; ++r) {
            const int srow = wv * 16 + rbase + r;
            const int d    = ct * 16 + lr;
            const int k    = nn * 4096 + srow * 64 + d;
            const int lane_z = (((k >> 3) & 3) << 4) + (bb & 15);
            const int kf   = k >> 5;
            const int j    = k & 7;
            const size_t zi = (((size_t)rt_z * 1536 + kf) * 64 + lane_z) * 8 + j;
            unsigned short h, l;
            split_bf16(o_[ct][r], h, l);
            Zh[zi] = h; Zl[zi] = l;
        }
}

// ---------------- Kernel 3: output projection — LDS-staged W, frag-order Z ----------------
// part[ksp][b][o] = sum_k Z[b][k] W[o][k]; KSPLIT=32, chunk=1536, BK=64.
// Wave-private W staging (each wave stages only its own 16 W rows via
// global_load_lds, XOR-swizzled source) -> NO __syncthreads anywhere.
__global__ __launch_bounds__(256) void k_lin(const unsigned short* __restrict__ Zh,
                                             const unsigned short* __restrict__ Zl,
                                             const float* __restrict__ W,
                                             float* __restrict__ part) {
    __shared__ float ldsw[2][4][16][64];   // [buf][wave][row][64 f32], swizzled content
    const int t  = threadIdx.x;
    const int wv = t >> 6, ln = t & 63;
    const int lr = ln & 15;
    const int o0   = blockIdx.x * 64;
    const int ksp  = blockIdx.y;
    const int kbeg = ksp * 1536;

    const f32x4 zero4 = {0.f, 0.f, 0.f, 0.f};
    f32x4 acc[4];
#pragma unroll
    for (int rt = 0; rt < 4; ++rt) acc[rt] = zero4;

    // staging lane geometry: instr i covers rows 4i..4i+3; lane -> (row, slot u)
    const int st_row = ln >> 4;                 // +4*i
    const int st_u   = ln & 15;                 // LDS 16B-unit slot within row

    // issue one K-step's staging (4 global_load_lds) into buf
#define STAGE(buf, kstep)                                                           \
    {                                                                               \
        const int k0f = kbeg + (kstep) * 64;                                        \
        _Pragma("unroll")                                                           \
        for (int i = 0; i < 4; ++i) {                                               \
            const int row_l = i * 4 + st_row;                                       \
            const int u_g   = st_u ^ (row_l & 7);                                   \
            const float* src = W + (size_t)(o0 + wv * 16 + row_l) * 49152 + k0f + u_g * 4; \
            __builtin_amdgcn_global_load_lds((gvoid_t*)src,                         \
                (svoid_t*)&ldsw[buf][wv][i * 4][0], 16, 0, 0);                      \
        }                                                                           \
    }

    STAGE(0, 0)
    for (int ts = 0; ts < 24; ++ts) {
        const int tn = (ts + 1 < 24) ? ts + 1 : 23;   // clamped (harmless re-stage)
        if ((ts + 1) & 1) STAGE(1, tn) else STAGE(0, tn)
        asm volatile("s_waitcnt vmcnt(4)" ::: "memory");   // stage(ts) complete; stage(ts+1) in flight
        const int buf = ts & 1;
        const int kf0 = ksp * 48 + ts * 2;
#pragma unroll
        for (int ks = 0; ks < 2; ++ks) {
            // B fragment: W row o0+wv*16+lr, k = ks*32 + (ln>>4)*8 .. +7 (swizzled read)
            const int u0 = ks * 8 + (ln >> 4) * 2;
            const char* rowp = (const char*)&ldsw[buf][wv][lr][0];
            float4 f0 = *reinterpret_cast<const float4*>(rowp + ((u0 ^ (lr & 7)) << 4));
            float4 f1 = *reinterpret_cast<const float4*>(rowp + (((u0 + 1) ^ (lr & 7)) << 4));
            bf16x8 wh, wl;
            split8(f0, f1, wh, wl);
            const size_t zoff = ((size_t)(kf0 + ks) * 64 + ln) * 8;
#pragma unroll
            for (int rt = 0; rt < 4; ++rt) {
                const size_t zi = (size_t)rt * 1536 * 64 * 8 + zoff;
                bf16x8 ah = *reinterpret_cast<const bf16x8*>(Zh + zi);
                bf16x8 al = *reinterpret_cast<const bf16x8*>(Zl + zi);
                acc[rt] = __builtin_amdgcn_mfma_f32_16x16x32_bf16(ah, wh, acc[rt], 0, 0, 0);
                acc[rt] = __builtin_amdgcn_mfma_f32_16x16x32_bf16(ah, wl, acc[rt], 0, 0, 0);
                acc[rt] = __builtin_amdgcn_mfma_f32_16x16x32_bf16(al, wh, acc[rt], 0, 0, 0);
            }
        }
    }
#undef STAGE

    const int rbase = (ln >> 4) * 4;
    const int ocol  = o0 + wv * 16 + lr;
#pragma unroll
    for (int rt = 0; rt < 4; ++rt)
#pragma unroll
        for (int r = 0; r < 4; ++r) {
            const int brow = rt * 16 + rbase + r;
            part[((size_t)ksp * 64 + brow) * 4096 + ocol] = acc[rt][r];
        }
}

// ---------------- Kernel 4: reduce 32 split-K partials + bias ----------------
__global__ __launch_bounds__(256) void k_reduce(const float* __restrict__ part,
                                                const float* __restrict__ bias,
                                                float* __restrict__ y) {
    const int idx = blockIdx.x * 256 + threadIdx.x;
    const int o = idx & 4095;
    const int b = idx >> 12;
    float s = bias[o];
#pragma unroll
    for (int ksp = 0; ksp < 32; ++ksp)
        s += part[((size_t)ksp * 64 + b) * 4096 + o];
    y[idx] = s;
}

extern "C" void kernel_launch(void* const* d_in, const int* in_sizes, int n_in,
                              void* d_out, int out_size, void* d_ws, size_t ws_size,
                              hipStream_t stream) {
    const float* x  = (const float*)d_in[0];
    const float* Wp = (const float*)d_in[1];
    const float* Wl = (const float*)d_in[2];
    const float* bl = (const float*)d_in[3];
    float* out = (float*)d_out;
    float* ws  = (float*)d_ws;

    float* qkv  = ws;                                        // dead after k_attn
    float* part = ws;                                        // reuses qkv region
    unsigned short* Zh = (unsigned short*)(ws + 9437184);
    unsigned short* Zl = (unsigned short*)(ws + 11010048);
    float* y    = out;
    float* msk  = out + 262144;

    hipLaunchKernelGGL(k_qkv,    dim3(18, 32), dim3(256), 0, stream, x, Wp, qkv);
    hipLaunchKernelGGL(k_attn,   dim3(768),    dim3(256), 0, stream, qkv, msk, Zh, Zl);
    hipLaunchKernelGGL(k_lin,    dim3(64, 32), dim3(256), 0, stream, Zh, Zl, Wl, part);
    hipLaunchKernelGGL(k_reduce, dim3(1024),   dim3(256), 0, stream, part, bl, y);
}